// Round 4
// baseline (252.117 us; speedup 1.0000x reference)
//
#include <hip/hip_runtime.h>

#define HH 384
#define WW 384
#define OUTD 370
#define NSHIFT 99

// ---- fused per-tile geometry: 32 wide x 24 tall ----
// R18 theory: the pin is LDS instruction-issue throughput (per-CU DS pipe).
// Evidence: occupancy (R16) and barrier count (R17) both no-ops; VALUBusy ~96
// is 2x-inflated by the gfx94x derived formula (SIMD-16 4cy assumption) ->
// real VALU duty ~48%; DS hand-count at measured b32=5.8cy/instr gives
// ~2790 cy/CU per 2279-cy iteration window = saturated.
// Fix: fewer/wider DS ops, same arithmetic:
//  - tmp now ROW-major (STR=36): horiz writes 2x ds_write_b128 (was 8x b32
//    strided). Write banks: quad=(r+2*oct) mod 8, 4 lanes/quad = even min.
//  - vert: 6-row strips, ONE image per thread (unit=tid>>1, img=tid&1):
//    12 b32 reads / 6 outputs (was 9/3). Img stride TIMG=1104 == 16 mod 32
//    -> P/G lanes hit disjoint bank halves, 0 conflicts.
//  - phase-2 |ep-eg| via DPP quad_perm xor-1 (VALU pipe has headroom);
//    both partners add the term -> final scale halved.
// L-tile layout and horiz reads untouched (LSTR==15 mod 32 bank law intact).
// Scalar VALU only (R6/R14: packed v2f regressed).
#define TW 32
#define TH 24
#define LSTR 47          // L stride (==15 mod 32)
#define LROWS 39         // 24 + 6 conv + 9 shift span
#define LPADSZ 1856      // 39*47=1833 padded to 32-mult
#define STR 36           // tmp row stride (mult of 4 for b128; ==4 mod 8 spreads write quads)
#define TIMG 1104        // per-image tmp size; ==16 mod 32 -> P/G bank-disjoint; mult of 4
#define NXT 12
#define NYT 16

#define G0 0.32465246735834974f   // exp(-9/8)
#define G1 0.6065306597126334f    // exp(-4/8)
#define G2 0.8824969025845955f    // exp(-1/8)
#define KS 0.039788735772973836f  // 1/(8*pi)
#define LOG2E 1.4426950408889634f

__device__ __forceinline__ float tap7(const float* v)
{
    return fmaf(G0, v[0] + v[6],
           fmaf(G1, v[1] + v[5],
           fmaf(G2, v[2] + v[4], v[3])));
}

__device__ __forceinline__ void shift_of(int s, int& sx, int& sy)
{
    int t = (s < 55) ? s : s + 1;    // skip (0,0)
    sx = t / 10 - 5;
    sy = t - (t / 10) * 10 - 5;
}

// partner-lane (xor 1) exchange on the VALU pipe (DPP quad_perm [1,0,3,2])
__device__ __forceinline__ float xor1(float x)
{
    return __int_as_float(
        __builtin_amdgcn_mov_dpp(__float_as_int(x), 0xB1, 0xF, 0xF, true));
}

__device__ __forceinline__ void load_tile(const float* __restrict__ img,
                                          int oy0, int ox0, float* L, int tid)
{
    for (int i = tid; i < LROWS * LSTR; i += 256) {
        int r = i / LSTR, c = i - r * LSTR;
        int gr = oy0 + r; if (gr >= HH) gr -= HH;   // circular wrap
        int gc = ox0 + c; if (gc >= WW) gc -= WW;
        L[i] = img[gr * WW + gc];
    }
}

// horizontal 7-tap over inline diff^2; 8 outputs -> row-major tmp, 2x b128
__device__ __forceinline__ void horiz8(const float* __restrict__ Lb,
                                       const float* __restrict__ cA,
                                       float* __restrict__ tb,
                                       int r, int c0, int sx, int sy)
{
    const float* Ls = &Lb[(r + 4 - sy) * LSTR + (c0 + 4 - sx)];
    float v[14];
#pragma unroll
    for (int t = 0; t < 14; ++t) { float d = cA[t] - Ls[t]; v[t] = d * d; }
    float4 o0 = make_float4(tap7(v + 0), tap7(v + 1), tap7(v + 2), tap7(v + 3));
    float4 o1 = make_float4(tap7(v + 4), tap7(v + 5), tap7(v + 6), tap7(v + 7));
    float4* o = (float4*)(tb + r * STR + c0);   // 16B-aligned: STR%4==0, c0%8==0
    o[0] = o0;
    o[1] = o1;
}

// vertical 7-tap, 6 outputs from 12 column values (one image per thread)
__device__ __forceinline__ void vert6(const float* __restrict__ tb,
                                      int vx, int vy0, float* D)
{
    const float* t = &tb[vy0 * STR + vx];
    float w[12];
#pragma unroll
    for (int j = 0; j < 12; ++j) w[j] = t[j * STR];
#pragma unroll
    for (int k = 0; k < 6; ++k) D[k] = KS * tap7(w + k);
}

extern "C" __global__ void __launch_bounds__(256, 3)
mind_fused(const float* __restrict__ pred, const float* __restrict__ gt,
           float* __restrict__ out)
{
    __shared__ __align__(16) float LP[LPADSZ];
    __shared__ __align__(16) float LG[LPADSZ];
    __shared__ __align__(16) float tmp[2][2][TIMG];   // [parity][img P=0/G=1]
    __shared__ float wred[4];
    const int tid = threadIdx.x;
    const int b = blockIdx.y;
    const int oy0 = ((int)blockIdx.x / NXT) * TH;
    const int ox0 = ((int)blockIdx.x % NXT) * TW;

    load_tile(pred + (size_t)b * HH * WW, oy0, ox0, LP, tid);
    load_tile(gt   + (size_t)b * HH * WW, oy0, ox0, LG, tid);

    // horiz: 120 units/image = 30 rows x 4 col-octets. PURE phases:
    // P on tid 0..119, G on tid 128..247 (no 32-lane phase mixes images).
    const bool hP = tid < 120;
    const bool hG = (tid >= 128) && (tid < 248);
    const bool hasH = hP || hG;
    const int hu = hP ? tid : (tid - 128);
    const int hr = hu >> 2, hc0 = (hu & 3) << 3;
    const float* Lh = hG ? LG : LP;
    const int himg = hG ? 1 : 0;

    // vert: 128 units (32 cols x 4 strips of 6 rows) x 2 images on 256 threads.
    // unit = tid>>1, img = tid&1 -> P/G adjacent lanes, DPP-xor1 pairing.
    const int vu = tid >> 1, vim = tid & 1;
    const int vx = vu & 31, vy0 = (vu >> 5) * 6;

    __syncthreads();

    float cA[14];
    if (hasH) {
        const float* p = &Lh[(hr + 4) * LSTR + hc0 + 4];
#pragma unroll
        for (int t = 0; t < 14; ++t) cA[t] = p[t];
    }

    // ---- phase 1: V (4 cardinals) and minD over 99 shifts (own image) ----
    float dm[6], vs[6];
#pragma unroll
    for (int k = 0; k < 6; ++k) { dm[k] = 1e30f; vs[k] = 0.f; }

    for (int s = 0; s < NSHIFT; ++s) {
        int sx, sy; shift_of(s, sx, sy);
        if (hasH) horiz8(Lh, cA, tmp[s & 1][himg], hr, hc0, sx, sy);
        __syncthreads();   // tmp[s&1] ready; parity alternation -> WAR safe
        float D[6];
        vert6(tmp[s & 1][vim], vx, vy0, D);
        const bool card = (sx * sx + sy * sy) == 1;
#pragma unroll
        for (int k = 0; k < 6; ++k) {
            dm[k] = fminf(dm[k], D[k]);
            if (card) vs[k] += D[k];
        }
    }

    // loss constants; invalid pixels get rv=0 -> e=exp2(0)=1 on BOTH partners
    // (same pixel) -> |ep-eg|=0 exactly, so phase 2 is fully branchless.
    float rv[6];
#pragma unroll
    for (int k = 0; k < 6; ++k) {
        int oy = oy0 + vy0 + k, ox = ox0 + vx;
        const bool valid = (oy < OUTD) && (ox < OUTD);
        rv[k] = valid ? LOG2E / (vs[k] * 0.25f + 1e-5f) : 0.f;
    }

    __syncthreads();   // phase boundary: protect buf-0 reuse against last vert read

    // ---- phase 2: recompute D, accumulate |exp2((m-D)*rv) - partner| ----
    float acc = 0.f;
    for (int s = 0; s < NSHIFT; ++s) {
        int sx, sy; shift_of(s, sx, sy);
        if (hasH) horiz8(Lh, cA, tmp[s & 1][himg], hr, hc0, sx, sy);
        __syncthreads();
        float D[6];
        vert6(tmp[s & 1][vim], vx, vy0, D);
#pragma unroll
        for (int k = 0; k < 6; ++k) {
            float e = exp2f((dm[k] - D[k]) * rv[k]);
            float ep = xor1(e);            // partner image, same pixel (VALU)
            acc += fabsf(e - ep);          // added by BOTH partners -> SC halved
        }
    }

#pragma unroll
    for (int off = 32; off > 0; off >>= 1) acc += __shfl_down(acc, off, 64);
    const int lane = tid & 63, wv = tid >> 6;
    if (lane == 0) wred[wv] = acc;
    __syncthreads();
    if (tid == 0) {
        const float SC = (float)(1.0 / 108424800.0);  // 1/(2*4*370*370*99): x2 pair-dup
        atomicAdd(out, (wred[0] + wred[1] + wred[2] + wred[3]) * SC);
    }
}

extern "C" void kernel_launch(void* const* d_in, const int* in_sizes, int n_in,
                              void* d_out, int out_size, void* d_ws, size_t ws_size,
                              hipStream_t stream)
{
    (void)in_sizes; (void)n_in; (void)out_size; (void)d_ws; (void)ws_size;
    const float* pred = (const float*)d_in[0];
    const float* gt   = (const float*)d_in[1];
    float* out = (float*)d_out;

    hipMemsetAsync(d_out, 0, sizeof(float), stream);

    dim3 g(NXT * NYT, 4, 1);   // 192 tiles x 4 batch = 768 blocks = 3/CU exact
    mind_fused<<<g, 256, 0, stream>>>(pred, gt, out);
}

// Round 5
// 234.869 us; speedup vs baseline: 1.0734x; 1.0734x over previous
//
#include <hip/hip_runtime.h>

#define HH 384
#define WW 384
#define OUTD 370
#define NSHIFT 99

// ---- fused per-tile geometry: 32 wide x 24 tall (R13 core, 187us) ----
// Ledger: R16 occupancy x1.33 -> 0; R17 barriers /2 -> 0; R18 DS-instrs -30%
// -> +19% REGRESSION (broke transposed-tmp consecutive reads). Conclusion:
// stall-dominated, time tracks the post-barrier dependent-load chain.
// R19: software-pipeline across the barrier. Per period: (a) ISSUE vert reads
// for shift s, (b) horiz for shift s+1 (~90 independent instrs hide (a)'s
// ~120cy LDS latency), (c) consume. Parity double-buffer makes it safe with
// the same single barrier/period: horiz(s+1) writes buf[(s+1)&1], vert(s)
// reads buf[s&1]; barrier drain orders reads vs the s+2 overwrite.
// Everything else R13-exact: bank law (LSTR==15 mod 32, TMS==-1 mod 32,
// pure-image horiz phases P=tid 0..119 / G=tid 128..247, 0 conflicts
// R14-verified), scalar VALU only (R6/R14/R18: packed/DPP regressed),
// ascending-s order -> bitwise-identical output (absmax 0).
#define TW 32
#define TH 24
#define LSTR 47          // L stride (==15 mod 32)
#define LROWS 39         // 24 + 6 conv + 9 shift span
#define LPADSZ 1856      // 39*47=1833 padded to 32-mult -> LG base bank-aligned
#define TMS 31           // tmp_T stride (==-1 mod 32)
#define TTSZ (TW * TMS)  // 992 dwords (32-mult)
#define NXT 12
#define NYT 16

#define G0 0.32465246735834974f   // exp(-9/8)
#define G1 0.6065306597126334f    // exp(-4/8)
#define G2 0.8824969025845955f    // exp(-1/8)
#define KS 0.039788735772973836f  // 1/(8*pi)
#define LOG2E 1.4426950408889634f

__device__ __forceinline__ float tap7(const float* v)
{
    return fmaf(G0, v[0] + v[6],
           fmaf(G1, v[1] + v[5],
           fmaf(G2, v[2] + v[4], v[3])));
}

__device__ __forceinline__ void shift_of(int s, int& sx, int& sy)
{
    int t = (s < 55) ? s : s + 1;    // skip (0,0)
    sx = t / 10 - 5;
    sy = t - (t / 10) * 10 - 5;
}

__device__ __forceinline__ void load_tile(const float* __restrict__ img,
                                          int oy0, int ox0, float* L, int tid)
{
    for (int i = tid; i < LROWS * LSTR; i += 256) {
        int r = i / LSTR, c = i - r * LSTR;
        int gr = oy0 + r; if (gr >= HH) gr -= HH;   // circular wrap
        int gc = ox0 + c; if (gc >= WW) gc -= WW;
        L[i] = img[gr * WW + gc];
    }
}

// horizontal 7-tap over inline diff^2; 8 outputs -> transposed tmp (R13 scalar core)
__device__ __forceinline__ void horiz8(const float* __restrict__ Lb,
                                       const float* __restrict__ cA,
                                       float* __restrict__ tb,
                                       int r, int c0, int sx, int sy)
{
    const float* Ls = &Lb[(r + 4 - sy) * LSTR + (c0 + 4 - sx)];
    float v[14];
#pragma unroll
    for (int t = 0; t < 14; ++t) { float d = cA[t] - Ls[t]; v[t] = d * d; }
    float* o = &tb[c0 * TMS + r];
#pragma unroll
    for (int k = 0; k < 8; ++k) o[k * TMS] = tap7(v + k);
}

// issue the 9 consecutive tmp_T reads for one image (latency hidden by caller)
__device__ __forceinline__ void vert_load(const float* __restrict__ tT,
                                          int vx, int vy0, float* w)
{
    const float* t = &tT[vx * TMS + vy0];
#pragma unroll
    for (int j = 0; j < 9; ++j) w[j] = t[j];
}

__device__ __forceinline__ void vert_calc(const float* __restrict__ w, float* D)
{
#pragma unroll
    for (int k = 0; k < 3; ++k) D[k] = KS * tap7(w + k);
}

extern "C" __global__ void __launch_bounds__(256, 3)
mind_fused(const float* __restrict__ pred, const float* __restrict__ gt,
           float* __restrict__ out)
{
    __shared__ float LP[LPADSZ];
    __shared__ float LG[LPADSZ];
    __shared__ float tTP[2][TTSZ];
    __shared__ float tTG[2][TTSZ];
    __shared__ float wred[4];
    const int tid = threadIdx.x;
    const int b = blockIdx.y;
    const int oy0 = ((int)blockIdx.x / NXT) * TH;
    const int ox0 = ((int)blockIdx.x % NXT) * TW;

    load_tile(pred + (size_t)b * HH * WW, oy0, ox0, LP, tid);
    load_tile(gt   + (size_t)b * HH * WW, oy0, ox0, LG, tid);

    // horiz: 120 units/image = 30 rows x 4 col-octets. PURE phases:
    // P on tid 0..119, G on tid 128..247 (no 32-lane phase mixes images).
    const bool hP = tid < 120;
    const bool hG = (tid >= 128) && (tid < 248);
    const bool hasH = hP || hG;
    const int hu = hP ? tid : (tid - 128);
    const int hr = hu >> 2, hc0 = (hu & 3) << 3;
    const float* Lh = hG ? LG : LP;
    float* const tb0 = hG ? tTG[0] : tTP[0];
    float* const tb1 = hG ? tTG[1] : tTP[1];

    // vert: all 256 = 32 cols x 8 strips of 3 rows, both images per thread
    const int vx = tid & 31, vy0 = (tid >> 5) * 3;

    __syncthreads();

    float cA[14];
    if (hasH) {
        const float* p = &Lh[(hr + 4) * LSTR + hc0 + 4];
#pragma unroll
        for (int t = 0; t < 14; ++t) cA[t] = p[t];
    }

    // ---- phase 1: V (4 cardinals) and minD over 99 shifts, both images ----
    float dmp[3], vsp[3], dmg[3], vsg[3];
#pragma unroll
    for (int k = 0; k < 3; ++k) { dmp[k] = 1e30f; vsp[k] = 0.f; dmg[k] = 1e30f; vsg[k] = 0.f; }

    {
        int sx, sy; shift_of(0, sx, sy);
        if (hasH) horiz8(Lh, cA, tb0, hr, hc0, sx, sy);   // prologue: s=0
        __syncthreads();
        for (int s = 0; s < NSHIFT; ++s) {
            // (a) issue vert reads for shift s (regs; latency hidden by (b))
            float wP[9], wG[9];
            vert_load(tTP[s & 1], vx, vy0, wP);
            vert_load(tTG[s & 1], vx, vy0, wG);
            // (b) horiz for shift s+1 into the opposite buffer
            int nsx = 0, nsy = 0;
            if (s + 1 < NSHIFT) {
                shift_of(s + 1, nsx, nsy);
                if (hasH) horiz8(Lh, cA, ((s + 1) & 1) ? tb1 : tb0, hr, hc0, nsx, nsy);
            }
            // (c) consume
            float Dp[3], Dg[3];
            vert_calc(wP, Dp);
            vert_calc(wG, Dg);
            const bool card = (sx * sx + sy * sy) == 1;
#pragma unroll
            for (int k = 0; k < 3; ++k) {
                dmp[k] = fminf(dmp[k], Dp[k]);
                dmg[k] = fminf(dmg[k], Dg[k]);
                if (card) { vsp[k] += Dp[k]; vsg[k] += Dg[k]; }
            }
            sx = nsx; sy = nsy;
            __syncthreads();   // orders: horiz(s+1) writes done; vert(s) reads drained
        }
    }

    // loss constants; invalid pixels get rv=0 -> ep=eg=exp2(0)=1 -> |ep-eg|=0
    // exactly, so the phase-2 loop is fully branchless.
    float rvp[3], rvg[3];
#pragma unroll
    for (int k = 0; k < 3; ++k) {
        int oy = oy0 + vy0 + k, ox = ox0 + vx;
        const bool valid = (oy < OUTD) && (ox < OUTD);
        rvp[k] = valid ? LOG2E / (vsp[k] * 0.25f + 1e-5f) : 0.f;
        rvg[k] = valid ? LOG2E / (vsg[k] * 0.25f + 1e-5f) : 0.f;
    }

    // ---- phase 2: recompute D, accumulate |exp2((m-D)*rv)p - (...)g| ----
    float acc = 0.f;
    {
        int sx, sy; shift_of(0, sx, sy);
        if (hasH) horiz8(Lh, cA, tb0, hr, hc0, sx, sy);   // prologue: s=0
        __syncthreads();
        for (int s = 0; s < NSHIFT; ++s) {
            float wP[9], wG[9];
            vert_load(tTP[s & 1], vx, vy0, wP);
            vert_load(tTG[s & 1], vx, vy0, wG);
            int nsx = 0, nsy = 0;
            if (s + 1 < NSHIFT) {
                shift_of(s + 1, nsx, nsy);
                if (hasH) horiz8(Lh, cA, ((s + 1) & 1) ? tb1 : tb0, hr, hc0, nsx, nsy);
            }
            float Dp[3], Dg[3];
            vert_calc(wP, Dp);
            vert_calc(wG, Dg);
#pragma unroll
            for (int k = 0; k < 3; ++k) {
                float ep = exp2f((dmp[k] - Dp[k]) * rvp[k]);
                float eg = exp2f((dmg[k] - Dg[k]) * rvg[k]);
                acc += fabsf(ep - eg);
            }
            sx = nsx; sy = nsy;
            __syncthreads();
        }
    }

#pragma unroll
    for (int off = 32; off > 0; off >>= 1) acc += __shfl_down(acc, off, 64);
    const int lane = tid & 63, wv = tid >> 6;
    if (lane == 0) wred[wv] = acc;
    __syncthreads();
    if (tid == 0) {
        const float SC = (float)(1.0 / 54212400.0);  // 1/(4*370*370*99)
        atomicAdd(out, (wred[0] + wred[1] + wred[2] + wred[3]) * SC);
    }
}

extern "C" void kernel_launch(void* const* d_in, const int* in_sizes, int n_in,
                              void* d_out, int out_size, void* d_ws, size_t ws_size,
                              hipStream_t stream)
{
    (void)in_sizes; (void)n_in; (void)out_size; (void)d_ws; (void)ws_size;
    const float* pred = (const float*)d_in[0];
    const float* gt   = (const float*)d_in[1];
    float* out = (float*)d_out;

    hipMemsetAsync(d_out, 0, sizeof(float), stream);

    dim3 g(NXT * NYT, 4, 1);   // 192 tiles x 4 batch = 768 blocks = 3/CU exact
    mind_fused<<<g, 256, 0, stream>>>(pred, gt, out);
}

// Round 6
// 227.954 us; speedup vs baseline: 1.1060x; 1.0303x over previous
//
#include <hip/hip_runtime.h>

#define HH 384
#define WW 384
#define OUTD 370

// ---- R20: axis-swapped separable conv, register-cached shifted columns ----
// Ledger: R16 occupancy x1.33 -> 0; R17 barriers /2 -> 0; R19 sw-pipeline -> -7%;
// R18 tmp relayout -> -19%. Reshuffles of the same instr stream never help ->
// binding resource = LDS instruction issue (pessimistic count ~2784 cy/CU per
// 2267-cy iteration window). R20 removes DS instructions algebraically:
//  - stage-1 = VERTICAL tap first. Shift list is sx-outer/sy-inner (ascending s),
//    so a fixed-sx group of 10 consecutive shifts reads the same 23-row column
//    span: load sC[23] to REGISTERS once per 10 shifts, diffs^2 from regs.
//    Input reads /10 (1386 -> 230 b32 per thread-phase).
//  - stage-2 = horizontal tap: 14 CONSECUTIVE dwords per 8 outputs (1.75/out).
//  - per-wave-uniform unit maps (57 s1-units + 24 s2-pairs per wave) -> all
//    SIMDs carry identical load.
// Order: ascending s everywhere -> cardinal vsum bitwise-identical; pixel
// grouping changes only (R16 precedent: absmax stayed 0).
// Banks: TSTR=39 (odd) -> stage-2 read phase {39*dv_r+8*oc} bijective mod 32;
// TIMG=936==8 mod 32 -> img-interleaved s2 phases 2-way max (free, m136);
// stage-1 reads/writes consecutive-dv_c -> distinct banks, straddles 2-way.
// All inner loops fully unrolled -> sC[a+off]/d[] indices compile-time (no scratch).
#define TW 32
#define TH 24
#define LSTR 47          // L stride (unchanged; load_tile proven)
#define LROWS 39
#define LPADSZ 1856      // 39*47=1833 padded; ==0 mod 32
#define TSTR 39          // Dv tmp row stride (odd -> s2 bank bijection)
#define TIMG 936         // 24*39; ==8 mod 32
#define NXT 12
#define NYT 16

#define G0 0.32465246735834974f   // exp(-9/8)
#define G1 0.6065306597126334f    // exp(-4/8)
#define G2 0.8824969025845955f    // exp(-1/8)
#define KS 0.039788735772973836f  // 1/(8*pi)
#define LOG2E 1.4426950408889634f

__device__ __forceinline__ float tap7(const float* v)
{
    return fmaf(G0, v[0] + v[6],
           fmaf(G1, v[1] + v[5],
           fmaf(G2, v[2] + v[4], v[3])));
}

// partner-lane (xor 1) exchange on the VALU pipe (DPP quad_perm [1,0,3,2])
__device__ __forceinline__ float xor1(float x)
{
    return __int_as_float(
        __builtin_amdgcn_mov_dpp(__float_as_int(x), 0xB1, 0xF, 0xF, true));
}

__device__ __forceinline__ void load_tile(const float* __restrict__ img,
                                          int oy0, int ox0, float* L, int tid)
{
    for (int i = tid; i < LROWS * LSTR; i += 256) {
        int r = i / LSTR, c = i - r * LSTR;
        int gr = oy0 + r; if (gr >= HH) gr -= HH;   // circular wrap
        int gc = ox0 + c; if (gc >= WW) gc -= WW;
        L[i] = img[gr * WW + gc];
    }
}

extern "C" __global__ void __launch_bounds__(256, 3)
mind_fused(const float* __restrict__ pred, const float* __restrict__ gt,
           float* __restrict__ out)
{
    __shared__ float LP[LPADSZ];
    __shared__ float LG[LPADSZ];
    __shared__ float tbuf[2][2][TIMG];   // [parity][img][dv_r*TSTR + dv_c]
    __shared__ float wred[4];
    const int tid = threadIdx.x;
    const int b = blockIdx.y;
    const int oy0 = ((int)blockIdx.x / NXT) * TH;
    const int ox0 = ((int)blockIdx.x % NXT) * TW;

    load_tile(pred + (size_t)b * HH * WW, oy0, ox0, LP, tid);
    load_tile(gt   + (size_t)b * HH * WW, oy0, ox0, LG, tid);

    const int wv = tid >> 6, ln = tid & 63;

    // stage-1 (vertical tap): 228 units = 2 img x (3 bands x 38 Dv-cols);
    // 57 units/wave -> every wave same load.
    const bool s1 = ln < 57;
    const int su = wv * 57 + ln;              // 0..227
    const int img1 = (su >= 114) ? 1 : 0;
    const int u1 = img1 ? su - 114 : su;      // 0..113
    const int band = u1 / 38;
    const int dv_c = u1 - band * 38;          // 0..37
    const int r0 = band * 8;                  // 0,8,16
    const float* Lh1 = img1 ? LG : LP;

    // stage-2 (horizontal tap): 192 units = 2 img x (24 rows x 4 col-octets);
    // 48 threads/wave as 24 adjacent (P,G) pairs -> DPP xor1 pairing.
    const bool s2 = ln < 48;
    const int u2 = wv * 24 + (ln >> 1);       // 0..95
    const int img2 = ln & 1;
    const int dv_r = u2 >> 2;                 // 0..23
    const int oc = u2 & 3;                    // col-octet

    __syncthreads();

    // shift-independent center column: 14 rows at (dv_c+4)
    float cC[14];
    if (s1) {
#pragma unroll
        for (int t = 0; t < 14; ++t)
            cC[t] = Lh1[(r0 + 4 + t) * LSTR + dv_c + 4];
    }

    // ---- phase 1: V (4 cardinals) and minD over 99 shifts ----
    float dm[8], vs[8];
#pragma unroll
    for (int k = 0; k < 8; ++k) { dm[k] = 1e30f; vs[k] = 0.f; }

    int p = 0;
    for (int gx = 0; gx < 10; ++gx) {
        const int sxg = gx - 5;
        float sC[23];
        if (s1) {
            const int cs = dv_c + 4 - sxg;    // 0..46
#pragma unroll
            for (int t = 0; t < 23; ++t) sC[t] = Lh1[(r0 + t) * LSTR + cs];
        }
#pragma unroll
        for (int j = 0; j < 10; ++j) {
            const int sy = j - 5;
            if (sxg == 0 && sy == 0) continue;   // uniform skip, no barrier
            const int off = 9 - j;               // = 4 - sy (compile-time)
            if (s1) {
                float d[14];
#pragma unroll
                for (int a = 0; a < 14; ++a) {
                    float dd = cC[a] - sC[a + off]; d[a] = dd * dd;
                }
                float* w = &tbuf[p][img1][dv_c];
#pragma unroll
                for (int k = 0; k < 8; ++k) w[(r0 + k) * TSTR] = tap7(d + k);
            }
            __syncthreads();
            if (s2) {
                const float* hvp = &tbuf[p][img2][dv_r * TSTR + oc * 8];
                float hv[14];
#pragma unroll
                for (int t = 0; t < 14; ++t) hv[t] = hvp[t];
                const bool card = (sxg * sxg + sy * sy) == 1;
#pragma unroll
                for (int k = 0; k < 8; ++k) {
                    float D = KS * tap7(hv + k);
                    dm[k] = fminf(dm[k], D);
                    if (card) vs[k] += D;
                }
            }
            p ^= 1;
        }
    }

    // loss constants; invalid pixels rv=0 -> e=1 on both partners -> |e-ep|=0
    float rv[8];
#pragma unroll
    for (int k = 0; k < 8; ++k) {
        const int oy = oy0 + dv_r, ox = ox0 + oc * 8 + k;
        const bool valid = s2 && (oy < OUTD) && (ox < OUTD);
        rv[k] = valid ? LOG2E / (vs[k] * 0.25f + 1e-5f) : 0.f;
    }

    __syncthreads();   // phase boundary: protect buf reuse against last s2 read

    // ---- phase 2: recompute D, accumulate |e - partner(e)| ----
    float acc = 0.f;
    p = 0;
    for (int gx = 0; gx < 10; ++gx) {
        const int sxg = gx - 5;
        float sC[23];
        if (s1) {
            const int cs = dv_c + 4 - sxg;
#pragma unroll
            for (int t = 0; t < 23; ++t) sC[t] = Lh1[(r0 + t) * LSTR + cs];
        }
#pragma unroll
        for (int j = 0; j < 10; ++j) {
            const int sy = j - 5;
            if (sxg == 0 && sy == 0) continue;
            const int off = 9 - j;
            if (s1) {
                float d[14];
#pragma unroll
                for (int a = 0; a < 14; ++a) {
                    float dd = cC[a] - sC[a + off]; d[a] = dd * dd;
                }
                float* w = &tbuf[p][img1][dv_c];
#pragma unroll
                for (int k = 0; k < 8; ++k) w[(r0 + k) * TSTR] = tap7(d + k);
            }
            __syncthreads();
            if (s2) {
                const float* hvp = &tbuf[p][img2][dv_r * TSTR + oc * 8];
                float hv[14];
#pragma unroll
                for (int t = 0; t < 14; ++t) hv[t] = hvp[t];
#pragma unroll
                for (int k = 0; k < 8; ++k) {
                    float D = KS * tap7(hv + k);
                    float e = exp2f((dm[k] - D) * rv[k]);
                    float ep = xor1(e);    // partner image, same pixel (VALU pipe)
                    acc += fabsf(e - ep);  // added by BOTH partners -> SC halved
                }
            }
            p ^= 1;
        }
    }

#pragma unroll
    for (int off = 32; off > 0; off >>= 1) acc += __shfl_down(acc, off, 64);
    if (ln == 0) wred[wv] = acc;
    __syncthreads();
    if (tid == 0) {
        const float SC = (float)(1.0 / 108424800.0);  // 1/(2*4*370*370*99)
        atomicAdd(out, (wred[0] + wred[1] + wred[2] + wred[3]) * SC);
    }
}

extern "C" void kernel_launch(void* const* d_in, const int* in_sizes, int n_in,
                              void* d_out, int out_size, void* d_ws, size_t ws_size,
                              hipStream_t stream)
{
    (void)in_sizes; (void)n_in; (void)out_size; (void)d_ws; (void)ws_size;
    const float* pred = (const float*)d_in[0];
    const float* gt   = (const float*)d_in[1];
    float* out = (float*)d_out;

    hipMemsetAsync(d_out, 0, sizeof(float), stream);

    dim3 g(NXT * NYT, 4, 1);   // 192 tiles x 4 batch = 768 blocks = 3/CU exact
    mind_fused<<<g, 256, 0, stream>>>(pred, gt, out);
}